// Round 7
// baseline (1937.763 us; speedup 1.0000x reference)
//
#include <hip/hip_runtime.h>
#include <math.h>

#define NW 64
#define NS 5
#define NQ 195
#define DIM 1536
#define NTOT 12800
#define NL 320
#define NU 12480
#define NUP 12544
#define ALPHA 0.2f
#define EPOCHS 20
#define EPSC 1e-6f
#define MAXIT 1000
#define SB_NB 49
#define NSLAB 7

typedef float f32x4 __attribute__((ext_vector_type(4)));
typedef short short8 __attribute__((ext_vector_type(8)));

// ---------------- helpers ----------------
__device__ inline float wave_sum(float x){
#pragma unroll
  for(int o=32;o;o>>=1) x += __shfl_xor(x,o);
  return x;
}
__device__ inline float bf2f(ushort h){
  union{uint u; float f;} c; c.u = ((uint)h)<<16; return c.f;
}
__device__ inline ushort f2bf(float x){
  union{float f; uint u;} c; c.f = x;
  uint r = c.u + 0x7FFFu + ((c.u>>16)&1u);
  return (ushort)(r>>16);
}
// async global->LDS, 16B per lane; LDS dest = wave-uniform base + lane*16 (linear)
__device__ inline void gld16(const ushort* g, ushort* l){
  __builtin_amdgcn_global_load_lds((const __attribute__((address_space(1))) void*)g,
                                   (__attribute__((address_space(3))) void*)l, 16, 0, 0);
}

// ---------------- K1: sqrt power transform + row l2norm -> Zhi bf16 ----------------
__global__ __launch_bounds__(256) void k_prep(const float* __restrict__ X, ushort* __restrict__ Zhi){
  int row = blockIdx.x*4 + (threadIdx.x>>6);
  int lane = threadIdx.x & 63;
  const float4* xp = (const float4*)(X + (size_t)row*DIM);
  float4 v[6]; float ss = 0.f;
#pragma unroll
  for(int q=0;q<6;q++){
    float4 t = xp[lane + 64*q];
    t.x = sqrtf(t.x+1e-6f); t.y = sqrtf(t.y+1e-6f); t.z = sqrtf(t.z+1e-6f); t.w = sqrtf(t.w+1e-6f);
    v[q]=t; ss += t.x*t.x+t.y*t.y+t.z*t.z+t.w*t.w;
  }
  ss = wave_sum(ss);
  float inv = 1.f / fmaxf(sqrtf(ss), 1e-12f);
#pragma unroll
  for(int q=0;q<6;q++){
    float4 t = v[q];
    ushort4 h;
    h.x=f2bf(t.x*inv); h.y=f2bf(t.y*inv); h.z=f2bf(t.z*inv); h.w=f2bf(t.w*inv);
    *(ushort4*)&Zhi[(size_t)row*DIM + 4*lane + 256*q] = h;
  }
}

// ---------------- K2a: segment column sums ----------------
__global__ __launch_bounds__(256) void k_colsum(const ushort* __restrict__ Zhi,
                                                float* __restrict__ csum_l, float* __restrict__ csum_u){
  int c0 = blockIdx.x*512 + 2*threadIdx.x;
  int r0 = blockIdx.y*128;
  float al0=0.f, al1=0.f, au0=0.f, au1=0.f;
  for(int r=r0; r<r0+128; r++){
    ushort2 h = *(const ushort2*)&Zhi[(size_t)r*DIM + c0];
    float x0 = bf2f(h.x), x1 = bf2f(h.y);
    if(r < NL){ al0+=x0; al1+=x1; } else { au0+=x0; au1+=x1; }
  }
  if(r0 < NL){ atomicAdd(&csum_l[c0], al0); atomicAdd(&csum_l[c0+1], al1); }
  if(r0+128 > NL){ atomicAdd(&csum_u[c0], au0); atomicAdd(&csum_u[c0+1], au1); }
}

// ---------------- K2b ----------------
__global__ void k_finalize_means(float* csum_l, float* csum_u){
  int idx = blockIdx.x*256 + threadIdx.x;
  if(idx < DIM) csum_l[idx] *= (1.0f/NL);
  else if(idx < 2*DIM) csum_u[idx-DIM] *= (1.0f/NU);
}

// ---------------- K3: center + row l2norm (in place) ----------------
__global__ __launch_bounds__(256) void k_center(ushort* __restrict__ Zhi,
                                                const float* __restrict__ cm_l, const float* __restrict__ cm_u){
  int row = blockIdx.x*4 + (threadIdx.x>>6);
  int lane = threadIdx.x & 63;
  const float4* cp = (const float4*)((row < NL) ? cm_l : cm_u);
  float4 v[6]; float ss = 0.f;
#pragma unroll
  for(int q=0;q<6;q++){
    ushort4 h = *(const ushort4*)&Zhi[(size_t)row*DIM + 4*lane + 256*q];
    float4 m = cp[lane + 64*q];
    float4 t;
    t.x = bf2f(h.x) - m.x; t.y = bf2f(h.y) - m.y;
    t.z = bf2f(h.z) - m.z; t.w = bf2f(h.w) - m.w;
    v[q]=t; ss += t.x*t.x+t.y*t.y+t.z*t.z+t.w*t.w;
  }
  ss = wave_sum(ss);
  float inv = 1.f / fmaxf(sqrtf(ss), 1e-12f);
#pragma unroll
  for(int q=0;q<6;q++){
    float4 t = v[q];
    ushort4 h;
    h.x=f2bf(t.x*inv); h.y=f2bf(t.y*inv); h.z=f2bf(t.z*inv); h.w=f2bf(t.w*inv);
    *(ushort4*)&Zhi[(size_t)row*DIM + 4*lane + 256*q] = h;
  }
}

// ---------------- K3b: tile-transpose unlabeled Z -> ZT[c][iu] (pitch NUP) ----------------
__global__ __launch_bounds__(256) void k_ztrans(const ushort* __restrict__ Zhi, ushort* __restrict__ ZT){
  __shared__ ushort T[64][66];
  int ti = blockIdx.x, tc = blockIdx.y;
  int t = threadIdx.x;
  int r = t>>2, ch = (t&3)*16;
  const ushort* src = Zhi + (size_t)(NL + ti*64 + r)*DIM + tc*64 + ch;
  short8 a = *(const short8*)src;
  short8 b = *(const short8*)(src+8);
#pragma unroll
  for(int k=0;k<8;k++){ T[r][ch+k] = (ushort)a[k]; T[r][ch+8+k] = (ushort)b[k]; }
  __syncthreads();
  short8 o0, o1;
#pragma unroll
  for(int k=0;k<8;k++){ o0[k] = (short)T[ch+k][r]; o1[k] = (short)T[ch+8+k][r]; }
  ushort* dst = ZT + (size_t)(tc*64 + r)*NUP + ti*64 + ch;
  *(short8*)dst = o0;
  *(short8*)(dst+8) = o1;
}

// ---------------- K3c: zero ZT pad cols [NU, NUP) ----------------
__global__ void k_ztpad(ushort* __restrict__ ZT){
  int idx = blockIdx.x*256 + threadIdx.x;   // < 1536*64
  int c = idx >> 6, j = idx & 63;
  if(c < DIM) ZT[(size_t)c*NUP + NU + j] = 0;
}

// ---------------- K4: init mus from labeled shots ----------------
__global__ void k_mus_init(const ushort* __restrict__ Zhi, float* __restrict__ mus){
  int w = blockIdx.x;
#pragma unroll
  for(int q=0;q<6;q++){
    int c = threadIdx.x + 256*q;
    float s = 0.f;
#pragma unroll
    for(int sh=0; sh<NS; sh++) s += bf2f(Zhi[(size_t)(sh*NW + w)*DIM + c]);
    mus[(size_t)w*DIM + c] = s * 0.2f;
  }
}

// ---------------- K4b: vprev = 1 ----------------
__global__ void k_vinit(float* __restrict__ vprev){
  if(threadIdx.x < 64) vprev[threadIdx.x] = 1.0f;
}

// ---------------- K4c: S[c] = 5 * sum_w mus0[w][c] ----------------
__global__ void k_slc(const float* __restrict__ mus, float* __restrict__ S){
  int c = blockIdx.x*256 + threadIdx.x;
  float s = 0.f;
  for(int w=0;w<64;w++) s += mus[(size_t)w*DIM + c];
  S[c] = 5.0f * s;
}

// ---------------- K4d: emus_lab = S[c] + (e-1)*5*mus0 ----------------
__global__ void k_elab(const float* __restrict__ mus, const float* __restrict__ S,
                       float* __restrict__ emus_lab){
  int idx = blockIdx.x*256 + threadIdx.x;
  int c = idx % DIM;
  emus_lab[idx] = S[c] + (expf(1.0f)-1.0f)*5.0f*mus[idx];
}

// ---------------- K5: initial epoch prep (e=0): munorm, masksum, stamps, mus->bf16 hi/lo ----------------
__global__ void k_epoch_prep(const float* __restrict__ mus, float* munorm, float* masksum,
                             int* stamps, ushort* __restrict__ mbh, ushort* __restrict__ mbl){
  int w = blockIdx.x;
  float ss = 0.f;
#pragma unroll
  for(int q=0;q<6;q++){
    int c = threadIdx.x + 256*q;
    float v = mus[(size_t)w*DIM + c];
    ss += v*v;
    ushort h = f2bf(v);
    mbh[(size_t)w*DIM + c] = h;
    mbl[(size_t)w*DIM + c] = f2bf(v - bf2f(h));
  }
  __shared__ float red[4];
  float wsu = wave_sum(ss);
  if((threadIdx.x&63)==0) red[threadIdx.x>>6]=wsu;
  __syncthreads();
  if(threadIdx.x==0){
    munorm[w] = red[0]+red[1]+red[2]+red[3];
    masksum[w] = 315.0f + 5.0f*expf(1.0f);
    if(w < SB_NB) stamps[w] = 0;
  }
}

// ---------------- K6 v4: dist via MFMA, K-split x4 -> atomicAdd fp32 partial dots into S ----------------
// grid dim3(195,4) x 256: block (b,ks) = samples [b*64,b*64+64) x 64 ways, K chunk range
// [ks*6, ks*6+6) of 64-wide chunks. 2-deep ring (48KB LDS -> 3 blocks/CU: inter-block
// overlap replaces the 4-deep pipeline; the old 96KB/1-block/CU structure had ZERO
// co-resident work to hide the per-chunk barrier). Tail: S[i][w] += acc (device-scope
// atomics, cross-XCD coherent). exp/d2 finalize moved into k_sinkhorn's load.
__device__ inline void k_dist_stage(ushort* sm, int buf, int k0,
                                    const ushort* Zb, const ushort* mbh, const ushort* mbl,
                                    int w, int rr, int c8){
  int base = buf*12288;
#pragma unroll
  for(int j=0;j<6;j++){
    int s = 4*j + w;                 // 0..23, wave-uniform
    int row = (s&7)*8 + rr;          // row within 64-row tile
    int off = k0 + ((c8 ^ (row&7))<<3);   // pre-swizzled source chunk
    const ushort* src; int dst;
    if(s < 8){        src = Zb  + (size_t)row*DIM + off; dst = base + s*512; }
    else if(s < 16){  src = mbh + (size_t)row*DIM + off; dst = base + 4096 + (s-8)*512; }
    else {            src = mbl + (size_t)row*DIM + off; dst = base + 8192 + (s-16)*512; }
    gld16(src, sm + dst);
  }
}

__global__ __launch_bounds__(256,3) void k_dist(const ushort* __restrict__ mbh, const ushort* __restrict__ mbl,
                                                const ushort* __restrict__ Zhi, float* __restrict__ S){
  __shared__ __align__(16) ushort sm[24576];   // 48 KB: 2 x (A 8KB + Bh 8KB + Bl 8KB)
  int t = threadIdx.x;
  int w = t>>6, lane = t&63;
  int l15 = lane&15, q = lane>>4;
  int rr = lane>>3, c8 = lane&7;
  int e7 = l15&7;
  int b = blockIdx.x, ks = blockIdx.y;
  const ushort* Zb = Zhi + (size_t)(NL + b*64)*DIM;
  f32x4 acc[4];
#pragma unroll
  for(int mt=0;mt<4;mt++) acc[mt] = (f32x4){0.f,0.f,0.f,0.f};

  int k0 = ks*384;                   // this block's 6 chunks: k0 .. k0+383
  // prologue: stage chunks 0,1 -> buf 0,1 (12 loads/wave outstanding)
  k_dist_stage(sm, 0, k0,      Zb, mbh, mbl, w, rr, c8);
  k_dist_stage(sm, 1, k0+64,   Zb, mbh, mbl, w, rr, c8);

  int brow = 16*w + l15;             // B-tile row = this lane's way
  for(int c=0;c<6;c++){
    if(c < 5) asm volatile("s_waitcnt vmcnt(6)" ::: "memory");   // chunk c landed, c+1 in flight
    else      asm volatile("s_waitcnt vmcnt(0)" ::: "memory");
    __builtin_amdgcn_sched_barrier(0);
    __builtin_amdgcn_s_barrier();     // all waves have chunk c
    __builtin_amdgcn_sched_barrier(0);
    const ushort* tb = sm + (c&1)*12288;
#pragma unroll
    for(int kt=0;kt<2;kt++){
      int sw = ((kt*4 + q) ^ e7)<<3;   // read-side swizzle (matches staged source)
      short8 bh = *(const short8*)&tb[4096 + brow*64 + sw];
      short8 bl = *(const short8*)&tb[8192 + brow*64 + sw];
#pragma unroll
      for(int mt=0;mt<4;mt++){
        short8 a = *(const short8*)&tb[(mt*16 + l15)*64 + sw];
        acc[mt] = __builtin_amdgcn_mfma_f32_16x16x32_bf16(a, bh, acc[mt], 0,0,0);
        acc[mt] = __builtin_amdgcn_mfma_f32_16x16x32_bf16(a, bl, acc[mt], 0,0,0);
      }
    }
    if(c+2 < 6){
      __builtin_amdgcn_s_barrier();   // all waves done reading buf c&1
      k_dist_stage(sm, c&1, k0 + (c+2)*64, Zb, mbh, mbl, w, rr, c8);
    }
  }

  // tail: accumulate partial dot into S (exp/d2 finalize happens in k_sinkhorn)
#pragma unroll
  for(int mt=0;mt<4;mt++)
#pragma unroll
    for(int r=0;r<4;r++)
      atomicAdd(&S[(size_t)(b*64 + mt*16 + q*4 + r)*NW + 16*w + l15], acc[mt][r]);
}

// ---------------- K7: persistent Sinkhorn (tmat colsums) with inline dist-finalize ----------------
// Loads fp32 partial dots S, computes kr = exp(-10*sqrt(max(1+|mu|^2-2s,0))) inline
// (one less bf16 rounding than the old Kbf path), and re-zeros its S row so the U region
// is all-zero again for the next epoch's k_dist/k_emus atomics.
__global__ __launch_bounds__(256,1) void k_sinkhorn(float* __restrict__ S,
                                                    ushort* __restrict__ MThi,
                                                    float* __restrict__ partials, int* __restrict__ stamps,
                                                    float* __restrict__ vprev, float* __restrict__ masksum,
                                                    const float* __restrict__ munorm){
  __shared__ __align__(16) float vsh[64];
  __shared__ float mnsh[64];
  __shared__ float tmat[256][33];
  __shared__ float tq[8][64];
  __shared__ float tcol[64];
  __shared__ float mred[4];
  __shared__ float ctrl[1];
  int t = threadIdx.x, b = blockIdx.x;
  int iu = b*256 + t;
  bool active = iu < NU;
  if(t < 64){ vsh[t] = vprev[t]; mnsh[t] = munorm[t]; }
  __syncthreads();
  float kr[64];
  if(active){
    float* sp = S + (size_t)iu*NW;
#pragma unroll
    for(int q=0;q<16;q++){
      float4 sv = *(const float4*)(sp + 4*q);
      kr[4*q+0] = expf(-10.0f*sqrtf(fmaxf(1.0f + mnsh[4*q+0] - 2.0f*sv.x, 0.0f)));
      kr[4*q+1] = expf(-10.0f*sqrtf(fmaxf(1.0f + mnsh[4*q+1] - 2.0f*sv.y, 0.0f)));
      kr[4*q+2] = expf(-10.0f*sqrtf(fmaxf(1.0f + mnsh[4*q+2] - 2.0f*sv.z, 0.0f)));
      kr[4*q+3] = expf(-10.0f*sqrtf(fmaxf(1.0f + mnsh[4*q+3] - 2.0f*sv.w, 0.0f)));
    }
    float4 z4 = (float4){0.f,0.f,0.f,0.f};
#pragma unroll
    for(int q=0;q<16;q++) *(float4*)(sp + 4*q) = z4;   // re-zero for next epoch
  } else {
#pragma unroll
    for(int j=0;j<64;j++) kr[j]=0.f;
  }
  float u = 1.0f, r_old = 0.0f;
  int n = 0;
  while(true){
    // fp64 row dot: keeps the convergence residual off the fp32 noise floor (eps=1e-6)
    double s = 0.0;
#pragma unroll
    for(int q=0;q<16;q++){
      float4 vv = *(const float4*)&vsh[4*q];
      s += (double)kr[4*q]*vv.x + (double)kr[4*q+1]*vv.y + (double)kr[4*q+2]*vv.z + (double)kr[4*q+3]*vv.w;
    }
    float sf = (float)s;
    float r = u * sf;
    float diff = fabsf(r - r_old);
    float u_new = (active && sf > 0.f) ? 1.0f/sf : 0.0f;
    {
      float wmx = diff;
#pragma unroll
      for(int o=32;o;o>>=1) wmx = fmaxf(wmx, __shfl_xor(wmx,o));
      if((t&63)==0) mred[t>>6] = wmx;
    }
#pragma unroll
    for(int h=0;h<2;h++){
#pragma unroll
      for(int jj=0;jj<32;jj++) tmat[t][jj] = kr[32*h+jj]*u_new;
      __syncthreads();
      {
        int j = t & 31, q = t >> 5;
        float ps = 0.f;
#pragma unroll
        for(int rr=0;rr<32;rr++) ps += tmat[q*32+rr][j];
        tq[q][j] = ps;
      }
      __syncthreads();
      if(t < 32) tcol[32*h + t] = tq[0][t]+tq[1][t]+tq[2][t]+tq[3][t]+tq[4][t]+tq[5][t]+tq[6][t]+tq[7][t];
      __syncthreads();
    }
    int buf = n & 1;
    float* P = partials + buf*(SB_NB*66) + b*66;
    if(t < 64){
      __hip_atomic_store(&P[t], tcol[t], __ATOMIC_RELAXED, __HIP_MEMORY_SCOPE_AGENT);
    } else if(t == 64){
      float bm = fmaxf(fmaxf(mred[0],mred[1]), fmaxf(mred[2],mred[3]));
      __hip_atomic_store(&P[64], bm, __ATOMIC_RELAXED, __HIP_MEMORY_SCOPE_AGENT);
    }
    __syncthreads();
    if(t == 0){
      __threadfence();
      __hip_atomic_store(&stamps[b], n+1, __ATOMIC_RELEASE, __HIP_MEMORY_SCOPE_AGENT);
    }
    if(t < SB_NB){
      while(__hip_atomic_load(&stamps[t], __ATOMIC_ACQUIRE, __HIP_MEMORY_SCOPE_AGENT) <= n){}
    }
    __syncthreads();
    {
      int j = t & 63, q4 = t >> 6;
      float ps = 0.f, pm = 0.f;
      const float* PB = partials + buf*(SB_NB*66);
      // 12 unconditional plain loads (pipeline into one latency exposure) + uniform tail
#pragma unroll
      for(int i=0;i<12;i++){
        int bb = q4 + 4*i;            // max 3+44 = 47 < 49, always valid
        ps += PB[bb*66 + j];
        pm = fmaxf(pm, PB[bb*66 + 64]);
      }
      if(q4 == 0){                    // bb = 48 handled only by group 0 (wave-uniform)
        ps += PB[48*66 + j];
        pm = fmaxf(pm, PB[48*66 + 64]);
      }
      tq[q4][j] = ps;
      if(j==0) mred[q4] = pm;
    }
    __syncthreads();
    if(t==0) ctrl[0] = fmaxf(fmaxf(mred[0],mred[1]), fmaxf(mred[2],mred[3]));
    __syncthreads();
    float M = ctrl[0];
    if(M <= EPSC || n >= MAXIT) break;
    u = u_new; r_old = r; n++;
    if(t < 64) vsh[t] = (float)NQ / (tq[0][t]+tq[1][t]+tq[2][t]+tq[3][t]);
    __syncthreads();
  }
  // final plan colsums -> masksum
#pragma unroll
  for(int h=0;h<2;h++){
#pragma unroll
    for(int jj=0;jj<32;jj++) tmat[t][jj] = kr[32*h+jj]*u;
    __syncthreads();
    {
      int j = t & 31, q = t >> 5;
      float ps = 0.f;
#pragma unroll
      for(int rr=0;rr<32;rr++) ps += tmat[q*32+rr][j];
      tq[q][j] = ps;
    }
    __syncthreads();
    if(t < 32) tcol[32*h + t] = tq[0][t]+tq[1][t]+tq[2][t]+tq[3][t]+tq[4][t]+tq[5][t]+tq[6][t]+tq[7][t];
    __syncthreads();
  }
  if(t < 64) atomicAdd(&masksum[t], tcol[t]*vsh[t]);
  // store plan transposed, bf16 hi only (pitch NUP; 49*256 == NUP exactly)
  if(active){
#pragma unroll
    for(int j=0;j<64;j++)
      MThi[(size_t)j*NUP + iu] = f2bf(kr[j]*u*vsh[j]);
  } else {
#pragma unroll
    for(int j=0;j<64;j++)
      MThi[(size_t)j*NUP + iu] = 0;
  }
  if(b==0 && t<64) vprev[t] = vsh[t];
}

// ---------------- K8 v3: emus via MFMA, LDS-staged ring -> atomicAdd into emus[64][1536] ----------------
// K-split blocks accumulate via device-scope atomics into a single buffer (zeroed by
// k_sinkhorn's S re-zero; k_mus_step re-zeros its row after reading).
__device__ inline void k_emus_stage(ushort* sm, int buf, int k0,
                                    const ushort* Ab, const ushort* Bb,
                                    int w, int rr, int c8){
  int base = buf*8192;
#pragma unroll
  for(int j=0;j<4;j++){
    int s = 4*j + w;                 // 0..15, wave-uniform
    int row = (s&7)*8 + rr;          // row within 64-row tile
    int off = k0 + ((c8 ^ (row&7))<<3);   // pre-swizzled source chunk
    const ushort* src; int dst;
    if(s < 8){ src = Ab + (size_t)row*NUP + off; dst = base + s*512; }
    else     { src = Bb + (size_t)row*NUP + off; dst = base + 4096 + (s-8)*512; }
    gld16(src, sm + dst);
  }
}

__global__ __launch_bounds__(256,1) void k_emus(const ushort* __restrict__ MThi, const ushort* __restrict__ ZThi,
                                                float* __restrict__ emus){
  __shared__ __align__(16) ushort sm[32768];   // 64 KB: 4 x (A 8KB + B 8KB)
  int t = threadIdx.x;
  int w = t>>6, lane = t&63;
  int l15 = lane&15, q = lane>>4;
  int rr = lane>>3, c8 = lane&7;
  int e7 = l15&7;
  int cx = blockIdx.x, iy = blockIdx.y;
  const ushort* Ab = MThi + iy*1792;                        // ways x cols
  const ushort* Bb = ZThi + (size_t)(cx*64)*NUP + iy*1792;  // dims x cols
  f32x4 acc[4];
#pragma unroll
  for(int mt=0;mt<4;mt++) acc[mt] = (f32x4){0.f,0.f,0.f,0.f};

  // prologue: stage chunks 0,1,2 -> buf 0,1,2 (12 loads/wave outstanding)
  k_emus_stage(sm, 0, 0,   Ab, Bb, w, rr, c8);
  k_emus_stage(sm, 1, 64,  Ab, Bb, w, rr, c8);
  k_emus_stage(sm, 2, 128, Ab, Bb, w, rr, c8);

  int brow = 16*w + l15;             // B-tile row = this lane's dim
  for(int c=0;c<28;c++){
    if(c < 26)      asm volatile("s_waitcnt vmcnt(8)" ::: "memory");
    else if(c==26)  asm volatile("s_waitcnt vmcnt(4)" ::: "memory");
    else            asm volatile("s_waitcnt vmcnt(0)" ::: "memory");
    __builtin_amdgcn_sched_barrier(0);
    __builtin_amdgcn_s_barrier();
    __builtin_amdgcn_sched_barrier(0);
    if(c+3 < 28)
      k_emus_stage(sm, (c+3)&3, (c+3)*64, Ab, Bb, w, rr, c8);
    const ushort* tb = sm + (c&3)*8192;
#pragma unroll
    for(int kt=0;kt<2;kt++){
      int sw = ((kt*4 + q) ^ e7)<<3;
      short8 bf = *(const short8*)&tb[4096 + brow*64 + sw];
#pragma unroll
      for(int mt=0;mt<4;mt++){
        short8 a = *(const short8*)&tb[(mt*16 + l15)*64 + sw];
        acc[mt] = __builtin_amdgcn_mfma_f32_16x16x32_bf16(a, bf, acc[mt], 0,0,0);
      }
    }
  }

  // accumulate: way = mt*16 + q*4 + r (C/D row), dim = cx*64 + 16w + l15 (C/D col)
#pragma unroll
  for(int mt=0;mt<4;mt++)
#pragma unroll
    for(int r=0;r<4;r++)
      atomicAdd(&emus[(size_t)(mt*16 + q*4 + r)*DIM + cx*64 + 16*w + l15], acc[mt][r]);
}

// ---------------- K9: fused mus update + next-epoch prep (single emus read + re-zero) ----------------
__global__ void k_mus_step(float* __restrict__ mus, const float* __restrict__ emus_lab,
                           float* __restrict__ emus, float* munorm, float* masksum,
                           int* stamps, ushort* __restrict__ mbh, ushort* __restrict__ mbl){
  int w = blockIdx.x;
  float msum = masksum[w];
  float ss = 0.f;
#pragma unroll
  for(int q=0;q<6;q++){
    int c = threadIdx.x + 256*q;
    size_t idx = (size_t)w*DIM + c;
    float e = emus_lab[idx] + emus[idx];
    emus[idx] = 0.f;                 // block-local re-zero (row w only) for next epoch
    float nm = mus[idx] + ALPHA*(e/msum - mus[idx]);
    mus[idx] = nm;
    ss += nm*nm;
    ushort h = f2bf(nm);
    mbh[idx] = h;
    mbl[idx] = f2bf(nm - bf2f(h));
  }
  __shared__ float red[4];
  float wsu = wave_sum(ss);
  if((threadIdx.x&63)==0) red[threadIdx.x>>6]=wsu;
  __syncthreads();
  if(threadIdx.x==0){
    munorm[w] = red[0]+red[1]+red[2]+red[3];
    masksum[w] = 315.0f + 5.0f*expf(1.0f);
    if(w < SB_NB) stamps[w] = 0;
  }
}

// ---------------- K10a: labeled onehot rows ----------------
__global__ void k_out_lab(const int* __restrict__ labels, float* __restrict__ out){
  int idx = blockIdx.x*256 + threadIdx.x;
  if(idx < NL*NW){
    int i = idx >> 6, w = idx & 63;
    out[idx] = (labels[i]==w) ? 1.0f : 0.0f;
  }
}

// ---------------- K10b: unlabeled rows: out = log(plan) ----------------
__global__ __launch_bounds__(256) void k_out_u(const ushort* __restrict__ MThi, float* __restrict__ out){
  __shared__ float P[64][68];
  int b = blockIdx.x;
  int iu0 = b*64;
  int t = threadIdx.x;
  int w = t>>2, ch = (t&3)*16;
  const ushort* ph = MThi + (size_t)w*NUP + iu0 + ch;
  short8 h0 = *(const short8*)ph, h1 = *(const short8*)(ph+8);
#pragma unroll
  for(int k=0;k<8;k++){
    P[ch+k][w]   = logf(bf2f((ushort)h0[k]));
    P[ch+8+k][w] = logf(bf2f((ushort)h1[k]));
  }
  __syncthreads();
  int r = t>>2, c0 = (t&3)*16;
  float4* dst = (float4*)(out + (size_t)(NL + iu0 + r)*NW + c0);
#pragma unroll
  for(int g=0;g<4;g++) dst[g] = *(float4*)&P[r][c0+4*g];
}

// ---------------- K11: accuracy ----------------
__global__ void k_acc(const ushort* __restrict__ MThi, const int* __restrict__ labels, float* matchcount){
  int iu = blockIdx.x*256 + threadIdx.x;
  float m = 0.f;
  if(iu < NU){
    float best = -1.f; int bj = 0;
#pragma unroll 8
    for(int w=0;w<64;w++){
      float v = bf2f(MThi[(size_t)w*NUP + iu]);
      if(v > best){ best = v; bj = w; }
    }
    m = (labels[NL+iu] == bj) ? 1.f : 0.f;
  }
  float ws = wave_sum(m);
  __shared__ float red[4];
  if((threadIdx.x&63)==0) red[threadIdx.x>>6]=ws;
  __syncthreads();
  if(threadIdx.x==0) atomicAdd(matchcount, red[0]+red[1]+red[2]+red[3]);
}

// ---------------- K12 ----------------
__global__ void k_fin(const float* matchcount, float* __restrict__ out){
  out[(size_t)NTOT*NW]     = (*matchcount) * (1.0f/(float)NU);
  out[(size_t)NTOT*NW + 1] = 0.0f;
}

// ---------------- launch ----------------
extern "C" void kernel_launch(void* const* d_in, const int* in_sizes, int n_in,
                              void* d_out, int out_size, void* d_ws, size_t ws_size,
                              hipStream_t stream){
  const float* X = (const float*)d_in[0];
  const int* labels = (const int*)d_in[1];
  float* out = (float*)d_out;
  float* ws = (float*)d_ws;

  // ws layout (float offsets), total 20,769,864 fl = 83.08 MB (< proven-safe 85.94 MB)
  float*  matchcount = ws + 0;
  float*  munorm     = ws + 4;
  float*  masksum    = ws + 68;
  float*  vprev      = ws + 132;
  float*  csum_l     = ws + 196;
  float*  csum_u     = ws + 1732;
  int*    stamps     = (int*)(ws + 3268);        // 49 ints (region to 3332)
  float*  partials   = ws + 3332;                // 2*49*66 = 6468 -> 9800
  float*  Slc        = ws + 9800;                // 1536 -> 11336
  float*  mus        = ws + 11336;               // 98304 -> 109640
  float*  emus_lab   = ws + 109640;              // 98304 -> 207944
  ushort* mbh        = (ushort*)(ws + 207944);   // 49152 fl -> 257096
  ushort* mbl        = (ushort*)(ws + 257096);   // -> 306248
  // union region U (798,720 fl -> 1,104,968): always-zero-between-uses invariant:
  //   S    [12480][64] fp32  = full U      live [k_dist atomics -> k_sinkhorn load+rezero]
  //   emus [64][1536]  fp32  = U[0:98304]  live [k_emus atomics -> k_mus_step read+rezero]
  float*  U          = ws + 306248;
  float*  S          = U;
  float*  emus       = U;
  ushort* MThi       = (ushort*)(ws + 1104968);  // 401,408 us = 200,704 fl -> 1,305,672
  ushort* Zhi        = (ushort*)(ws + 1305672);  // 9,830,400 fl -> 11,136,072
  ushort* ZThi       = (ushort*)(ws + 11136072); // 9,633,792 fl -> 20,769,864
  if(ws_size < (size_t)20769864*4) return;

  hipMemsetAsync(ws, 0, 3332*sizeof(float), stream);
  hipMemsetAsync(U, 0, (size_t)798720*sizeof(float), stream);   // S zero (once; kernels maintain it)

  k_prep<<<3200,256,0,stream>>>(X, Zhi);
  k_colsum<<<dim3(3,100),256,0,stream>>>(Zhi, csum_l, csum_u);
  k_finalize_means<<<12,256,0,stream>>>(csum_l, csum_u);
  k_center<<<3200,256,0,stream>>>(Zhi, csum_l, csum_u);
  k_ztrans<<<dim3(195,24),256,0,stream>>>(Zhi, ZThi);
  k_ztpad<<<384,256,0,stream>>>(ZThi);
  k_mus_init<<<64,256,0,stream>>>(Zhi, mus);
  k_vinit<<<1,64,0,stream>>>(vprev);
  k_slc<<<6,256,0,stream>>>(mus, Slc);
  k_elab<<<384,256,0,stream>>>(mus, Slc, emus_lab);
  k_epoch_prep<<<64,256,0,stream>>>(mus, munorm, masksum, stamps, mbh, mbl);

  for(int e=0; e<=EPOCHS; e++){
    k_dist<<<dim3(195,4),256,0,stream>>>(mbh, mbl, Zhi, S);
    k_sinkhorn<<<SB_NB,256,0,stream>>>(S, MThi, partials, stamps, vprev, masksum, munorm);
    if(e < EPOCHS){
      k_emus<<<dim3(24,NSLAB),256,0,stream>>>(MThi, ZThi, emus);
      k_mus_step<<<64,256,0,stream>>>(mus, emus_lab, emus, munorm, masksum, stamps, mbh, mbl);
    }
  }
  k_out_lab<<<80,256,0,stream>>>(labels, out);
  k_out_u<<<195,256,0,stream>>>(MThi, out);
  k_acc<<<49,256,0,stream>>>(MThi, labels, matchcount);
  k_fin<<<1,1,0,stream>>>(matchcount, out);
}

// Round 8
// 1606.622 us; speedup vs baseline: 1.2061x; 1.2061x over previous
//
#include <hip/hip_runtime.h>
#include <math.h>

#define NW 64
#define NS 5
#define NQ 195
#define DIM 1536
#define NTOT 12800
#define NL 320
#define NU 12480
#define NUP 12544
#define ALPHA 0.2f
#define EPOCHS 20
#define EPSC 1e-6f
#define MAXIT 1000
#define SB_NB 49
#define NSLAB 7

typedef float f32x4 __attribute__((ext_vector_type(4)));
typedef short short8 __attribute__((ext_vector_type(8)));

// ---------------- helpers ----------------
__device__ inline float wave_sum(float x){
#pragma unroll
  for(int o=32;o;o>>=1) x += __shfl_xor(x,o);
  return x;
}
__device__ inline float bf2f(ushort h){
  union{uint u; float f;} c; c.u = ((uint)h)<<16; return c.f;
}
__device__ inline ushort f2bf(float x){
  union{float f; uint u;} c; c.f = x;
  uint r = c.u + 0x7FFFu + ((c.u>>16)&1u);
  return (ushort)(r>>16);
}
// async global->LDS, 16B per lane; LDS dest = wave-uniform base + lane*16 (linear)
__device__ inline void gld16(const ushort* g, ushort* l){
  __builtin_amdgcn_global_load_lds((const __attribute__((address_space(1))) void*)g,
                                   (__attribute__((address_space(3))) void*)l, 16, 0, 0);
}

// ---------------- K1: sqrt power transform + row l2norm -> Zhi bf16 ----------------
__global__ __launch_bounds__(256) void k_prep(const float* __restrict__ X, ushort* __restrict__ Zhi){
  int row = blockIdx.x*4 + (threadIdx.x>>6);
  int lane = threadIdx.x & 63;
  const float4* xp = (const float4*)(X + (size_t)row*DIM);
  float4 v[6]; float ss = 0.f;
#pragma unroll
  for(int q=0;q<6;q++){
    float4 t = xp[lane + 64*q];
    t.x = sqrtf(t.x+1e-6f); t.y = sqrtf(t.y+1e-6f); t.z = sqrtf(t.z+1e-6f); t.w = sqrtf(t.w+1e-6f);
    v[q]=t; ss += t.x*t.x+t.y*t.y+t.z*t.z+t.w*t.w;
  }
  ss = wave_sum(ss);
  float inv = 1.f / fmaxf(sqrtf(ss), 1e-12f);
#pragma unroll
  for(int q=0;q<6;q++){
    float4 t = v[q];
    ushort4 h;
    h.x=f2bf(t.x*inv); h.y=f2bf(t.y*inv); h.z=f2bf(t.z*inv); h.w=f2bf(t.w*inv);
    *(ushort4*)&Zhi[(size_t)row*DIM + 4*lane + 256*q] = h;
  }
}

// ---------------- K2a: segment column sums ----------------
__global__ __launch_bounds__(256) void k_colsum(const ushort* __restrict__ Zhi,
                                                float* __restrict__ csum_l, float* __restrict__ csum_u){
  int c0 = blockIdx.x*512 + 2*threadIdx.x;
  int r0 = blockIdx.y*128;
  float al0=0.f, al1=0.f, au0=0.f, au1=0.f;
  for(int r=r0; r<r0+128; r++){
    ushort2 h = *(const ushort2*)&Zhi[(size_t)r*DIM + c0];
    float x0 = bf2f(h.x), x1 = bf2f(h.y);
    if(r < NL){ al0+=x0; al1+=x1; } else { au0+=x0; au1+=x1; }
  }
  if(r0 < NL){ atomicAdd(&csum_l[c0], al0); atomicAdd(&csum_l[c0+1], al1); }
  if(r0+128 > NL){ atomicAdd(&csum_u[c0], au0); atomicAdd(&csum_u[c0+1], au1); }
}

// ---------------- K2b ----------------
__global__ void k_finalize_means(float* csum_l, float* csum_u){
  int idx = blockIdx.x*256 + threadIdx.x;
  if(idx < DIM) csum_l[idx] *= (1.0f/NL);
  else if(idx < 2*DIM) csum_u[idx-DIM] *= (1.0f/NU);
}

// ---------------- K3: center + row l2norm (in place) ----------------
__global__ __launch_bounds__(256) void k_center(ushort* __restrict__ Zhi,
                                                const float* __restrict__ cm_l, const float* __restrict__ cm_u){
  int row = blockIdx.x*4 + (threadIdx.x>>6);
  int lane = threadIdx.x & 63;
  const float4* cp = (const float4*)((row < NL) ? cm_l : cm_u);
  float4 v[6]; float ss = 0.f;
#pragma unroll
  for(int q=0;q<6;q++){
    ushort4 h = *(const ushort4*)&Zhi[(size_t)row*DIM + 4*lane + 256*q];
    float4 m = cp[lane + 64*q];
    float4 t;
    t.x = bf2f(h.x) - m.x; t.y = bf2f(h.y) - m.y;
    t.z = bf2f(h.z) - m.z; t.w = bf2f(h.w) - m.w;
    v[q]=t; ss += t.x*t.x+t.y*t.y+t.z*t.z+t.w*t.w;
  }
  ss = wave_sum(ss);
  float inv = 1.f / fmaxf(sqrtf(ss), 1e-12f);
#pragma unroll
  for(int q=0;q<6;q++){
    float4 t = v[q];
    ushort4 h;
    h.x=f2bf(t.x*inv); h.y=f2bf(t.y*inv); h.z=f2bf(t.z*inv); h.w=f2bf(t.w*inv);
    *(ushort4*)&Zhi[(size_t)row*DIM + 4*lane + 256*q] = h;
  }
}

// ---------------- K3b: tile-transpose unlabeled Z -> ZT[c][iu] (pitch NUP) ----------------
__global__ __launch_bounds__(256) void k_ztrans(const ushort* __restrict__ Zhi, ushort* __restrict__ ZT){
  __shared__ ushort T[64][66];
  int ti = blockIdx.x, tc = blockIdx.y;
  int t = threadIdx.x;
  int r = t>>2, ch = (t&3)*16;
  const ushort* src = Zhi + (size_t)(NL + ti*64 + r)*DIM + tc*64 + ch;
  short8 a = *(const short8*)src;
  short8 b = *(const short8*)(src+8);
#pragma unroll
  for(int k=0;k<8;k++){ T[r][ch+k] = (ushort)a[k]; T[r][ch+8+k] = (ushort)b[k]; }
  __syncthreads();
  short8 o0, o1;
#pragma unroll
  for(int k=0;k<8;k++){ o0[k] = (short)T[ch+k][r]; o1[k] = (short)T[ch+8+k][r]; }
  ushort* dst = ZT + (size_t)(tc*64 + r)*NUP + ti*64 + ch;
  *(short8*)dst = o0;
  *(short8*)(dst+8) = o1;
}

// ---------------- K3c: zero ZT pad cols [NU, NUP) ----------------
__global__ void k_ztpad(ushort* __restrict__ ZT){
  int idx = blockIdx.x*256 + threadIdx.x;   // < 1536*64
  int c = idx >> 6, j = idx & 63;
  if(c < DIM) ZT[(size_t)c*NUP + NU + j] = 0;
}

// ---------------- K4: init mus from labeled shots ----------------
__global__ void k_mus_init(const ushort* __restrict__ Zhi, float* __restrict__ mus){
  int w = blockIdx.x;
#pragma unroll
  for(int q=0;q<6;q++){
    int c = threadIdx.x + 256*q;
    float s = 0.f;
#pragma unroll
    for(int sh=0; sh<NS; sh++) s += bf2f(Zhi[(size_t)(sh*NW + w)*DIM + c]);
    mus[(size_t)w*DIM + c] = s * 0.2f;
  }
}

// ---------------- K4b: vprev = 1 ----------------
__global__ void k_vinit(float* __restrict__ vprev){
  if(threadIdx.x < 64) vprev[threadIdx.x] = 1.0f;
}

// ---------------- K4c: S[c] = 5 * sum_w mus0[w][c] ----------------
__global__ void k_slc(const float* __restrict__ mus, float* __restrict__ S){
  int c = blockIdx.x*256 + threadIdx.x;
  float s = 0.f;
  for(int w=0;w<64;w++) s += mus[(size_t)w*DIM + c];
  S[c] = 5.0f * s;
}

// ---------------- K4d: emus_lab = S[c] + (e-1)*5*mus0 ----------------
__global__ void k_elab(const float* __restrict__ mus, const float* __restrict__ S,
                       float* __restrict__ emus_lab){
  int idx = blockIdx.x*256 + threadIdx.x;
  int c = idx % DIM;
  emus_lab[idx] = S[c] + (expf(1.0f)-1.0f)*5.0f*mus[idx];
}

// ---------------- K5: initial epoch prep (e=0): munorm, masksum, stamps, mus->bf16 hi/lo ----------------
__global__ void k_epoch_prep(const float* __restrict__ mus, float* munorm, float* masksum,
                             int* stamps, ushort* __restrict__ mbh, ushort* __restrict__ mbl){
  int w = blockIdx.x;
  float ss = 0.f;
#pragma unroll
  for(int q=0;q<6;q++){
    int c = threadIdx.x + 256*q;
    float v = mus[(size_t)w*DIM + c];
    ss += v*v;
    ushort h = f2bf(v);
    mbh[(size_t)w*DIM + c] = h;
    mbl[(size_t)w*DIM + c] = f2bf(v - bf2f(h));
  }
  __shared__ float red[4];
  float wsu = wave_sum(ss);
  if((threadIdx.x&63)==0) red[threadIdx.x>>6]=wsu;
  __syncthreads();
  if(threadIdx.x==0){
    munorm[w] = red[0]+red[1]+red[2]+red[3];
    masksum[w] = 315.0f + 5.0f*expf(1.0f);
    if(w < SB_NB) stamps[w] = 0;
  }
}

// ---------------- K6 v3: dist via MFMA, M=64 blocks, 4-deep global_load_lds ring ----------------
__device__ inline void k_dist_stage(ushort* sm, int buf, int k0,
                                    const ushort* Zb, const ushort* mbh, const ushort* mbl,
                                    int w, int rr, int c8){
  int base = buf*12288;
#pragma unroll
  for(int j=0;j<6;j++){
    int s = 4*j + w;                 // 0..23, wave-uniform
    int row = (s&7)*8 + rr;          // row within 64-row tile
    int off = k0 + ((c8 ^ (row&7))<<3);   // pre-swizzled source chunk
    const ushort* src; int dst;
    if(s < 8){        src = Zb  + (size_t)row*DIM + off; dst = base + s*512; }
    else if(s < 16){  src = mbh + (size_t)row*DIM + off; dst = base + 4096 + (s-8)*512; }
    else {            src = mbl + (size_t)row*DIM + off; dst = base + 8192 + (s-16)*512; }
    gld16(src, sm + dst);
  }
}

__global__ __launch_bounds__(256,1) void k_dist(const ushort* __restrict__ mbh, const ushort* __restrict__ mbl,
                                                const ushort* __restrict__ Zhi, const float* __restrict__ munorm,
                                                ushort* __restrict__ Kbf){
  __shared__ __align__(16) ushort sm[49152];   // 96 KB: 4 x (A 8KB + Bh 8KB + Bl 8KB)
  int t = threadIdx.x;
  int w = t>>6, lane = t&63;
  int l15 = lane&15, q = lane>>4;
  int rr = lane>>3, c8 = lane&7;
  int e7 = l15&7;
  int b = blockIdx.x;
  const ushort* Zb = Zhi + (size_t)(NL + b*64)*DIM;
  float mn = munorm[16*w + l15];
  f32x4 acc[4];
#pragma unroll
  for(int mt=0;mt<4;mt++) acc[mt] = (f32x4){0.f,0.f,0.f,0.f};

  // prologue: stage chunks 0,1,2 -> buf 0,1,2 (18 loads/wave outstanding)
  k_dist_stage(sm, 0, 0,   Zb, mbh, mbl, w, rr, c8);
  k_dist_stage(sm, 1, 64,  Zb, mbh, mbl, w, rr, c8);
  k_dist_stage(sm, 2, 128, Zb, mbh, mbl, w, rr, c8);

  int brow = 16*w + l15;             // B-tile row = this lane's way
  for(int c=0;c<24;c++){
    // wait for chunk c to land, leave c+1/c+2 in flight (T4: never 0 in steady state)
    if(c < 22)      asm volatile("s_waitcnt vmcnt(12)" ::: "memory");
    else if(c==22)  asm volatile("s_waitcnt vmcnt(6)"  ::: "memory");
    else            asm volatile("s_waitcnt vmcnt(0)"  ::: "memory");
    __builtin_amdgcn_sched_barrier(0);
    __builtin_amdgcn_s_barrier();     // all waves: chunk c landed; compute(c-1) done
    __builtin_amdgcn_sched_barrier(0);
    if(c+3 < 24)
      k_dist_stage(sm, (c+3)&3, (c+3)*64, Zb, mbh, mbl, w, rr, c8);
    const ushort* tb = sm + (c&3)*12288;
#pragma unroll
    for(int kt=0;kt<2;kt++){
      int sw = ((kt*4 + q) ^ e7)<<3;   // read-side swizzle (matches staged source)
      short8 bh = *(const short8*)&tb[4096 + brow*64 + sw];
      short8 bl = *(const short8*)&tb[8192 + brow*64 + sw];
#pragma unroll
      for(int mt=0;mt<4;mt++){
        short8 a = *(const short8*)&tb[(mt*16 + l15)*64 + sw];
        acc[mt] = __builtin_amdgcn_mfma_f32_16x16x32_bf16(a, bh, acc[mt], 0,0,0);
        acc[mt] = __builtin_amdgcn_mfma_f32_16x16x32_bf16(a, bl, acc[mt], 0,0,0);
      }
    }
  }

  // tail: d2 = 1 + |mu|^2 - 2 s ; Kbf = bf16(exp(-10 sqrt(max(d2,0))))
#pragma unroll
  for(int mt=0;mt<4;mt++)
#pragma unroll
    for(int r=0;r<4;r++){
      float d2 = 1.0f + mn - 2.0f*acc[mt][r];
      Kbf[(size_t)(b*64 + mt*16 + q*4 + r)*NW + 16*w + l15] =
        f2bf(expf(-10.0f * sqrtf(fmaxf(d2, 0.0f))));
    }
}

// ---------------- K7 v3: persistent Sinkhorn, single-pass tmat colsum ----------------
// Same proven sync protocol as round-6 (stamps, double-buffered partials, plain-load
// read-back). Local colsum done in ONE pass over tmat[256][65] (odd stride: write
// (t+j)%32 and read (row+j)%32 are both 2-way = free) with 4 row-groups of 64; the
// P-store reads tq[0..3] directly (tcol stage removed). 7 barriers/iter vs 11.
__global__ __launch_bounds__(256,1) void k_sinkhorn(const ushort* __restrict__ Kbf,
                                                    ushort* __restrict__ MThi,
                                                    float* __restrict__ partials, int* __restrict__ stamps,
                                                    float* __restrict__ vprev, float* __restrict__ masksum){
  __shared__ __align__(16) float vsh[64];
  __shared__ float tmat[256][65];
  __shared__ float tq[4][64];
  __shared__ float mred[4];
  __shared__ float ctrl[1];
  int t = threadIdx.x, b = blockIdx.x;
  int iu = b*256 + t;
  bool active = iu < NU;
  int jrd = t & 63, qrd = t >> 6;    // colsum read roles (wave-uniform qrd)
  float kr[64];
  if(active){
    const ushort* kp = Kbf + (size_t)iu*NW;
#pragma unroll
    for(int q=0;q<8;q++){
      short8 hh = *(const short8*)(kp + 8*q);
#pragma unroll
      for(int i=0;i<8;i++) kr[8*q+i] = bf2f((ushort)hh[i]);
    }
  } else {
#pragma unroll
    for(int j=0;j<64;j++) kr[j]=0.f;
  }
  if(t < 64) vsh[t] = vprev[t];
  float u = 1.0f, r_old = 0.0f;
  __syncthreads();
  int n = 0;
  while(true){
    // fp64 row dot: keeps the convergence residual off the fp32 noise floor (eps=1e-6)
    double s = 0.0;
#pragma unroll
    for(int q=0;q<16;q++){
      float4 vv = *(const float4*)&vsh[4*q];
      s += (double)kr[4*q]*vv.x + (double)kr[4*q+1]*vv.y + (double)kr[4*q+2]*vv.z + (double)kr[4*q+3]*vv.w;
    }
    float sf = (float)s;
    float r = u * sf;
    float diff = fabsf(r - r_old);
    float u_new = (active && sf > 0.f) ? 1.0f/sf : 0.0f;
    {
      float wmx = diff;
#pragma unroll
      for(int o=32;o;o>>=1) wmx = fmaxf(wmx, __shfl_xor(wmx,o));
      if((t&63)==0) mred[t>>6] = wmx;
    }
    // single-pass: scaled row into tmat, then 4x64 partial colsums
#pragma unroll
    for(int jj=0;jj<64;jj++) tmat[t][jj] = kr[jj]*u_new;
    __syncthreads();
    {
      float ps = 0.f;
#pragma unroll
      for(int rr=0;rr<64;rr++) ps += tmat[qrd*64+rr][jrd];
      tq[qrd][jrd] = ps;
    }
    __syncthreads();
    int buf = n & 1;
    float* P = partials + buf*(SB_NB*66) + b*66;
    if(t < 64){
      __hip_atomic_store(&P[t], tq[0][t]+tq[1][t]+tq[2][t]+tq[3][t],
                         __ATOMIC_RELAXED, __HIP_MEMORY_SCOPE_AGENT);
    } else if(t == 64){
      float bm = fmaxf(fmaxf(mred[0],mred[1]), fmaxf(mred[2],mred[3]));
      __hip_atomic_store(&P[64], bm, __ATOMIC_RELAXED, __HIP_MEMORY_SCOPE_AGENT);
    }
    __syncthreads();
    if(t == 0){
      __threadfence();
      __hip_atomic_store(&stamps[b], n+1, __ATOMIC_RELEASE, __HIP_MEMORY_SCOPE_AGENT);
    }
    if(t < SB_NB){
      while(__hip_atomic_load(&stamps[t], __ATOMIC_ACQUIRE, __HIP_MEMORY_SCOPE_AGENT) <= n){}
    }
    __syncthreads();
    {
      int j = t & 63, q4 = t >> 6;
      float ps = 0.f, pm = 0.f;
      const float* PB = partials + buf*(SB_NB*66);
      // 12 unconditional plain loads (pipeline into one latency exposure) + uniform tail
#pragma unroll
      for(int i=0;i<12;i++){
        int bb = q4 + 4*i;            // max 3+44 = 47 < 49, always valid
        ps += PB[bb*66 + j];
        pm = fmaxf(pm, PB[bb*66 + 64]);
      }
      if(q4 == 0){                    // bb = 48 handled only by group 0 (wave-uniform)
        ps += PB[48*66 + j];
        pm = fmaxf(pm, PB[48*66 + 64]);
      }
      tq[q4][j] = ps;
      if(j==0) mred[q4] = pm;
    }
    __syncthreads();
    if(t==0) ctrl[0] = fmaxf(fmaxf(mred[0],mred[1]), fmaxf(mred[2],mred[3]));
    __syncthreads();
    float M = ctrl[0];
    if(M <= EPSC || n >= MAXIT) break;
    u = u_new; r_old = r; n++;
    if(t < 64) vsh[t] = (float)NQ / (tq[0][t]+tq[1][t]+tq[2][t]+tq[3][t]);
    __syncthreads();
  }
  // final plan colsums -> masksum (single pass, scaled by final u)
#pragma unroll
  for(int jj=0;jj<64;jj++) tmat[t][jj] = kr[jj]*u;
  __syncthreads();
  {
    float ps = 0.f;
#pragma unroll
    for(int rr=0;rr<64;rr++) ps += tmat[qrd*64+rr][jrd];
    tq[qrd][jrd] = ps;
  }
  __syncthreads();
  if(t < 64) atomicAdd(&masksum[t], (tq[0][t]+tq[1][t]+tq[2][t]+tq[3][t])*vsh[t]);
  // store plan transposed, bf16 hi only (pitch NUP; 49*256 == NUP exactly)
  if(active){
#pragma unroll
    for(int j=0;j<64;j++)
      MThi[(size_t)j*NUP + iu] = f2bf(kr[j]*u*vsh[j]);
  } else {
#pragma unroll
    for(int j=0;j<64;j++)
      MThi[(size_t)j*NUP + iu] = 0;
  }
  if(b==0 && t<64) vprev[t] = vsh[t];
}

// ---------------- K8 v2: emus via MFMA, LDS-staged 4-deep global_load_lds ring ----------------
__device__ inline void k_emus_stage(ushort* sm, int buf, int k0,
                                    const ushort* Ab, const ushort* Bb,
                                    int w, int rr, int c8){
  int base = buf*8192;
#pragma unroll
  for(int j=0;j<4;j++){
    int s = 4*j + w;                 // 0..15, wave-uniform
    int row = (s&7)*8 + rr;          // row within 64-row tile
    int off = k0 + ((c8 ^ (row&7))<<3);   // pre-swizzled source chunk
    const ushort* src; int dst;
    if(s < 8){ src = Ab + (size_t)row*NUP + off; dst = base + s*512; }
    else     { src = Bb + (size_t)row*NUP + off; dst = base + 4096 + (s-8)*512; }
    gld16(src, sm + dst);
  }
}

__global__ __launch_bounds__(256,1) void k_emus(const ushort* __restrict__ MThi, const ushort* __restrict__ ZThi,
                                                float* __restrict__ part){
  __shared__ __align__(16) ushort sm[32768];   // 64 KB: 4 x (A 8KB + B 8KB)
  int t = threadIdx.x;
  int w = t>>6, lane = t&63;
  int l15 = lane&15, q = lane>>4;
  int rr = lane>>3, c8 = lane&7;
  int e7 = l15&7;
  int cx = blockIdx.x, iy = blockIdx.y;
  const ushort* Ab = MThi + iy*1792;                        // ways x cols
  const ushort* Bb = ZThi + (size_t)(cx*64)*NUP + iy*1792;  // dims x cols
  f32x4 acc[4];
#pragma unroll
  for(int mt=0;mt<4;mt++) acc[mt] = (f32x4){0.f,0.f,0.f,0.f};

  // prologue: stage chunks 0,1,2 -> buf 0,1,2 (12 loads/wave outstanding)
  k_emus_stage(sm, 0, 0,   Ab, Bb, w, rr, c8);
  k_emus_stage(sm, 1, 64,  Ab, Bb, w, rr, c8);
  k_emus_stage(sm, 2, 128, Ab, Bb, w, rr, c8);

  int brow = 16*w + l15;             // B-tile row = this lane's dim
  for(int c=0;c<28;c++){
    if(c < 26)      asm volatile("s_waitcnt vmcnt(8)" ::: "memory");
    else if(c==26)  asm volatile("s_waitcnt vmcnt(4)" ::: "memory");
    else            asm volatile("s_waitcnt vmcnt(0)" ::: "memory");
    __builtin_amdgcn_sched_barrier(0);
    __builtin_amdgcn_s_barrier();
    __builtin_amdgcn_sched_barrier(0);
    if(c+3 < 28)
      k_emus_stage(sm, (c+3)&3, (c+3)*64, Ab, Bb, w, rr, c8);
    const ushort* tb = sm + (c&3)*8192;
#pragma unroll
    for(int kt=0;kt<2;kt++){
      int sw = ((kt*4 + q) ^ e7)<<3;
      short8 bf = *(const short8*)&tb[4096 + brow*64 + sw];
#pragma unroll
      for(int mt=0;mt<4;mt++){
        short8 a = *(const short8*)&tb[(mt*16 + l15)*64 + sw];
        acc[mt] = __builtin_amdgcn_mfma_f32_16x16x32_bf16(a, bf, acc[mt], 0,0,0);
      }
    }
  }

  // store: way = mt*16 + q*4 + r (C/D row), dim = cx*64 + 16w + l15 (C/D col)
  float* dst = part + (size_t)iy*(NW*DIM);
#pragma unroll
  for(int mt=0;mt<4;mt++)
#pragma unroll
    for(int r=0;r<4;r++)
      dst[(size_t)(mt*16 + q*4 + r)*DIM + cx*64 + 16*w + l15] = acc[mt][r];
}

// ---------------- K9: fused mus update + next-epoch prep ----------------
__global__ void k_mus_step(float* __restrict__ mus, const float* __restrict__ emus_lab,
                           const float* __restrict__ part, float* munorm, float* masksum,
                           int* stamps, ushort* __restrict__ mbh, ushort* __restrict__ mbl){
  int w = blockIdx.x;
  float msum = masksum[w];
  float ss = 0.f;
#pragma unroll
  for(int q=0;q<6;q++){
    int c = threadIdx.x + 256*q;
    size_t idx = (size_t)w*DIM + c;
    float e = emus_lab[idx];
#pragma unroll
    for(int s=0;s<NSLAB;s++) e += part[(size_t)s*(NW*DIM) + idx];
    float nm = mus[idx] + ALPHA*(e/msum - mus[idx]);
    mus[idx] = nm;
    ss += nm*nm;
    ushort h = f2bf(nm);
    mbh[idx] = h;
    mbl[idx] = f2bf(nm - bf2f(h));
  }
  __shared__ float red[4];
  float wsu = wave_sum(ss);
  if((threadIdx.x&63)==0) red[threadIdx.x>>6]=wsu;
  __syncthreads();
  if(threadIdx.x==0){
    munorm[w] = red[0]+red[1]+red[2]+red[3];
    masksum[w] = 315.0f + 5.0f*expf(1.0f);
    if(w < SB_NB) stamps[w] = 0;
  }
}

// ---------------- K10a: labeled onehot rows ----------------
__global__ void k_out_lab(const int* __restrict__ labels, float* __restrict__ out){
  int idx = blockIdx.x*256 + threadIdx.x;
  if(idx < NL*NW){
    int i = idx >> 6, w = idx & 63;
    out[idx] = (labels[i]==w) ? 1.0f : 0.0f;
  }
}

// ---------------- K10b: unlabeled rows: out = log(plan) ----------------
__global__ __launch_bounds__(256) void k_out_u(const ushort* __restrict__ MThi, float* __restrict__ out){
  __shared__ float P[64][68];
  int b = blockIdx.x;
  int iu0 = b*64;
  int t = threadIdx.x;
  int w = t>>2, ch = (t&3)*16;
  const ushort* ph = MThi + (size_t)w*NUP + iu0 + ch;
  short8 h0 = *(const short8*)ph, h1 = *(const short8*)(ph+8);
#pragma unroll
  for(int k=0;k<8;k++){
    P[ch+k][w]   = logf(bf2f((ushort)h0[k]));
    P[ch+8+k][w] = logf(bf2f((ushort)h1[k]));
  }
  __syncthreads();
  int r = t>>2, c0 = (t&3)*16;
  float4* dst = (float4*)(out + (size_t)(NL + iu0 + r)*NW + c0);
#pragma unroll
  for(int g=0;g<4;g++) dst[g] = *(float4*)&P[r][c0+4*g];
}

// ---------------- K11: accuracy ----------------
__global__ void k_acc(const ushort* __restrict__ MThi, const int* __restrict__ labels, float* matchcount){
  int iu = blockIdx.x*256 + threadIdx.x;
  float m = 0.f;
  if(iu < NU){
    float best = -1.f; int bj = 0;
#pragma unroll 8
    for(int w=0;w<64;w++){
      float v = bf2f(MThi[(size_t)w*NUP + iu]);
      if(v > best){ best = v; bj = w; }
    }
    m = (labels[NL+iu] == bj) ? 1.f : 0.f;
  }
  float ws = wave_sum(m);
  __shared__ float red[4];
  if((threadIdx.x&63)==0) red[threadIdx.x>>6]=ws;
  __syncthreads();
  if(threadIdx.x==0) atomicAdd(matchcount, red[0]+red[1]+red[2]+red[3]);
}

// ---------------- K12 ----------------
__global__ void k_fin(const float* matchcount, float* __restrict__ out){
  out[(size_t)NTOT*NW]     = (*matchcount) * (1.0f/(float)NU);
  out[(size_t)NTOT*NW + 1] = 0.0f;
}

// ---------------- launch ----------------
extern "C" void kernel_launch(void* const* d_in, const int* in_sizes, int n_in,
                              void* d_out, int out_size, void* d_ws, size_t ws_size,
                              hipStream_t stream){
  const float* X = (const float*)d_in[0];
  const int* labels = (const int*)d_in[1];
  float* out = (float*)d_out;
  float* ws = (float*)d_ws;

  // ws layout (float offsets), total 20,757,576 fl = 83.0 MB (< proven-safe 85.94 MB)
  float*  matchcount = ws + 0;
  float*  munorm     = ws + 4;
  float*  masksum    = ws + 68;
  float*  vprev      = ws + 132;
  float*  csum_l     = ws + 196;
  float*  csum_u     = ws + 1732;
  int*    stamps     = (int*)(ws + 3268);        // 49 ints (region to 3332)
  float*  partials   = ws + 3332;                // 2*49*66 = 6468 -> 9800
  float*  Slc        = ws + 9800;                // 1536 -> 11336
  float*  mus        = ws + 11336;               // 98304 -> 109640
  float*  emus_lab   = ws + 109640;              // 98304 -> 207944
  ushort* mbh        = (ushort*)(ws + 207944);   // 49152 fl -> 257096
  ushort* mbl        = (ushort*)(ws + 257096);   // -> 306248
  // union region U (786,432 fl -> 1,092,680): lifetimes disjoint within an epoch:
  //   Kbf  (798,720 us = 399,360 fl)  live [k_dist -> k_sinkhorn load]
  //   part (7*98,304 = 688,128 fl)    live [k_emus -> k_mus_step]
  float*  U          = ws + 306248;
  ushort* Kbf        = (ushort*)U;
  float*  part       = U;
  ushort* MThi       = (ushort*)(ws + 1092680);  // 401,408 us = 200,704 fl -> 1,293,384
  ushort* Zhi        = (ushort*)(ws + 1293384);  // 9,830,400 fl -> 11,123,784
  ushort* ZThi       = (ushort*)(ws + 11123784); // 9,633,792 fl -> 20,757,576
  if(ws_size < (size_t)20757576*4) return;

  hipMemsetAsync(ws, 0, 3332*sizeof(float), stream);

  k_prep<<<3200,256,0,stream>>>(X, Zhi);
  k_colsum<<<dim3(3,100),256,0,stream>>>(Zhi, csum_l, csum_u);
  k_finalize_means<<<12,256,0,stream>>>(csum_l, csum_u);
  k_center<<<3200,256,0,stream>>>(Zhi, csum_l, csum_u);
  k_ztrans<<<dim3(195,24),256,0,stream>>>(Zhi, ZThi);
  k_ztpad<<<384,256,0,stream>>>(ZThi);
  k_mus_init<<<64,256,0,stream>>>(Zhi, mus);
  k_vinit<<<1,64,0,stream>>>(vprev);
  k_slc<<<6,256,0,stream>>>(mus, Slc);
  k_elab<<<384,256,0,stream>>>(mus, Slc, emus_lab);
  k_epoch_prep<<<64,256,0,stream>>>(mus, munorm, masksum, stamps, mbh, mbl);

  for(int e=0; e<=EPOCHS; e++){
    k_dist<<<195,256,0,stream>>>(mbh, mbl, Zhi, munorm, Kbf);
    k_sinkhorn<<<SB_NB,256,0,stream>>>(Kbf, MThi, partials, stamps, vprev, masksum);
    if(e < EPOCHS){
      k_emus<<<dim3(24,NSLAB),256,0,stream>>>(MThi, ZThi, part);
      k_mus_step<<<64,256,0,stream>>>(mus, emus_lab, part, munorm, masksum, stamps, mbh, mbl);
    }
  }
  k_out_lab<<<80,256,0,stream>>>(labels, out);
  k_out_u<<<195,256,0,stream>>>(MThi, out);
  k_acc<<<49,256,0,stream>>>(MThi, labels, matchcount);
  k_fin<<<1,1,0,stream>>>(matchcount, out);
}

// Round 9
// 1434.890 us; speedup vs baseline: 1.3505x; 1.1197x over previous
//
#include <hip/hip_runtime.h>
#include <math.h>

#define NW 64
#define NS 5
#define NQ 195
#define DIM 1536
#define NTOT 12800
#define NL 320
#define NU 12480
#define NUP 12544
#define ALPHA 0.2f
#define EPOCHS 20
#define EPSC 1e-6f
#define MAXIT 1000
#define SB_NB 49
#define NSLAB 7

typedef float f32x4 __attribute__((ext_vector_type(4)));
typedef short short8 __attribute__((ext_vector_type(8)));

// ---------------- helpers ----------------
__device__ inline float wave_sum(float x){
#pragma unroll
  for(int o=32;o;o>>=1) x += __shfl_xor(x,o);
  return x;
}
__device__ inline float bf2f(ushort h){
  union{uint u; float f;} c; c.u = ((uint)h)<<16; return c.f;
}
__device__ inline ushort f2bf(float x){
  union{float f; uint u;} c; c.f = x;
  uint r = c.u + 0x7FFFu + ((c.u>>16)&1u);
  return (ushort)(r>>16);
}
// async global->LDS, 16B per lane; LDS dest = wave-uniform base + lane*16 (linear)
__device__ inline void gld16(const ushort* g, ushort* l){
  __builtin_amdgcn_global_load_lds((const __attribute__((address_space(1))) void*)g,
                                   (__attribute__((address_space(3))) void*)l, 16, 0, 0);
}

// ---------------- K1: sqrt power transform + row l2norm -> Zhi bf16 ----------------
__global__ __launch_bounds__(256) void k_prep(const float* __restrict__ X, ushort* __restrict__ Zhi){
  int row = blockIdx.x*4 + (threadIdx.x>>6);
  int lane = threadIdx.x & 63;
  const float4* xp = (const float4*)(X + (size_t)row*DIM);
  float4 v[6]; float ss = 0.f;
#pragma unroll
  for(int q=0;q<6;q++){
    float4 t = xp[lane + 64*q];
    t.x = sqrtf(t.x+1e-6f); t.y = sqrtf(t.y+1e-6f); t.z = sqrtf(t.z+1e-6f); t.w = sqrtf(t.w+1e-6f);
    v[q]=t; ss += t.x*t.x+t.y*t.y+t.z*t.z+t.w*t.w;
  }
  ss = wave_sum(ss);
  float inv = 1.f / fmaxf(sqrtf(ss), 1e-12f);
#pragma unroll
  for(int q=0;q<6;q++){
    float4 t = v[q];
    ushort4 h;
    h.x=f2bf(t.x*inv); h.y=f2bf(t.y*inv); h.z=f2bf(t.z*inv); h.w=f2bf(t.w*inv);
    *(ushort4*)&Zhi[(size_t)row*DIM + 4*lane + 256*q] = h;
  }
}

// ---------------- K2a: segment column sums ----------------
__global__ __launch_bounds__(256) void k_colsum(const ushort* __restrict__ Zhi,
                                                float* __restrict__ csum_l, float* __restrict__ csum_u){
  int c0 = blockIdx.x*512 + 2*threadIdx.x;
  int r0 = blockIdx.y*128;
  float al0=0.f, al1=0.f, au0=0.f, au1=0.f;
  for(int r=r0; r<r0+128; r++){
    ushort2 h = *(const ushort2*)&Zhi[(size_t)r*DIM + c0];
    float x0 = bf2f(h.x), x1 = bf2f(h.y);
    if(r < NL){ al0+=x0; al1+=x1; } else { au0+=x0; au1+=x1; }
  }
  if(r0 < NL){ atomicAdd(&csum_l[c0], al0); atomicAdd(&csum_l[c0+1], al1); }
  if(r0+128 > NL){ atomicAdd(&csum_u[c0], au0); atomicAdd(&csum_u[c0+1], au1); }
}

// ---------------- K2b ----------------
__global__ void k_finalize_means(float* csum_l, float* csum_u){
  int idx = blockIdx.x*256 + threadIdx.x;
  if(idx < DIM) csum_l[idx] *= (1.0f/NL);
  else if(idx < 2*DIM) csum_u[idx-DIM] *= (1.0f/NU);
}

// ---------------- K3: center + row l2norm (in place) ----------------
__global__ __launch_bounds__(256) void k_center(ushort* __restrict__ Zhi,
                                                const float* __restrict__ cm_l, const float* __restrict__ cm_u){
  int row = blockIdx.x*4 + (threadIdx.x>>6);
  int lane = threadIdx.x & 63;
  const float4* cp = (const float4*)((row < NL) ? cm_l : cm_u);
  float4 v[6]; float ss = 0.f;
#pragma unroll
  for(int q=0;q<6;q++){
    ushort4 h = *(const ushort4*)&Zhi[(size_t)row*DIM + 4*lane + 256*q];
    float4 m = cp[lane + 64*q];
    float4 t;
    t.x = bf2f(h.x) - m.x; t.y = bf2f(h.y) - m.y;
    t.z = bf2f(h.z) - m.z; t.w = bf2f(h.w) - m.w;
    v[q]=t; ss += t.x*t.x+t.y*t.y+t.z*t.z+t.w*t.w;
  }
  ss = wave_sum(ss);
  float inv = 1.f / fmaxf(sqrtf(ss), 1e-12f);
#pragma unroll
  for(int q=0;q<6;q++){
    float4 t = v[q];
    ushort4 h;
    h.x=f2bf(t.x*inv); h.y=f2bf(t.y*inv); h.z=f2bf(t.z*inv); h.w=f2bf(t.w*inv);
    *(ushort4*)&Zhi[(size_t)row*DIM + 4*lane + 256*q] = h;
  }
}

// ---------------- K3b: tile-transpose unlabeled Z -> ZT[c][iu] (pitch NUP) ----------------
__global__ __launch_bounds__(256) void k_ztrans(const ushort* __restrict__ Zhi, ushort* __restrict__ ZT){
  __shared__ ushort T[64][66];
  int ti = blockIdx.x, tc = blockIdx.y;
  int t = threadIdx.x;
  int r = t>>2, ch = (t&3)*16;
  const ushort* src = Zhi + (size_t)(NL + ti*64 + r)*DIM + tc*64 + ch;
  short8 a = *(const short8*)src;
  short8 b = *(const short8*)(src+8);
#pragma unroll
  for(int k=0;k<8;k++){ T[r][ch+k] = (ushort)a[k]; T[r][ch+8+k] = (ushort)b[k]; }
  __syncthreads();
  short8 o0, o1;
#pragma unroll
  for(int k=0;k<8;k++){ o0[k] = (short)T[ch+k][r]; o1[k] = (short)T[ch+8+k][r]; }
  ushort* dst = ZT + (size_t)(tc*64 + r)*NUP + ti*64 + ch;
  *(short8*)dst = o0;
  *(short8*)(dst+8) = o1;
}

// ---------------- K3c: zero ZT pad cols [NU, NUP) ----------------
__global__ void k_ztpad(ushort* __restrict__ ZT){
  int idx = blockIdx.x*256 + threadIdx.x;   // < 1536*64
  int c = idx >> 6, j = idx & 63;
  if(c < DIM) ZT[(size_t)c*NUP + NU + j] = 0;
}

// ---------------- K4: init mus from labeled shots ----------------
__global__ void k_mus_init(const ushort* __restrict__ Zhi, float* __restrict__ mus){
  int w = blockIdx.x;
#pragma unroll
  for(int q=0;q<6;q++){
    int c = threadIdx.x + 256*q;
    float s = 0.f;
#pragma unroll
    for(int sh=0; sh<NS; sh++) s += bf2f(Zhi[(size_t)(sh*NW + w)*DIM + c]);
    mus[(size_t)w*DIM + c] = s * 0.2f;
  }
}

// ---------------- K4b: vprev = 1 ----------------
__global__ void k_vinit(float* __restrict__ vprev){
  if(threadIdx.x < 64) vprev[threadIdx.x] = 1.0f;
}

// ---------------- K4c: S[c] = 5 * sum_w mus0[w][c] ----------------
__global__ void k_slc(const float* __restrict__ mus, float* __restrict__ S){
  int c = blockIdx.x*256 + threadIdx.x;
  float s = 0.f;
  for(int w=0;w<64;w++) s += mus[(size_t)w*DIM + c];
  S[c] = 5.0f * s;
}

// ---------------- K4d: emus_lab = S[c] + (e-1)*5*mus0 ----------------
__global__ void k_elab(const float* __restrict__ mus, const float* __restrict__ S,
                       float* __restrict__ emus_lab){
  int idx = blockIdx.x*256 + threadIdx.x;
  int c = idx % DIM;
  emus_lab[idx] = S[c] + (expf(1.0f)-1.0f)*5.0f*mus[idx];
}

// ---------------- K5: initial epoch prep (e=0): munorm, masksum, stamps, mus->bf16 hi/lo ----------------
__global__ void k_epoch_prep(const float* __restrict__ mus, float* munorm, float* masksum,
                             int* stamps, ushort* __restrict__ mbh, ushort* __restrict__ mbl){
  int w = blockIdx.x;
  float ss = 0.f;
#pragma unroll
  for(int q=0;q<6;q++){
    int c = threadIdx.x + 256*q;
    float v = mus[(size_t)w*DIM + c];
    ss += v*v;
    ushort h = f2bf(v);
    mbh[(size_t)w*DIM + c] = h;
    mbl[(size_t)w*DIM + c] = f2bf(v - bf2f(h));
  }
  __shared__ float red[4];
  float wsu = wave_sum(ss);
  if((threadIdx.x&63)==0) red[threadIdx.x>>6]=wsu;
  __syncthreads();
  if(threadIdx.x==0){
    munorm[w] = red[0]+red[1]+red[2]+red[3];
    masksum[w] = 315.0f + 5.0f*expf(1.0f);
    if(w < SB_NB) stamps[w] = 0;
  }
}

// ---------------- K6 v5: dist via MFMA, 8 waves (2Mx4N) on 64x64 tile, 4-deep ring ----------------
// grid 195 x 512: same tile/LDS/barrier/vmcnt structure as the proven v3, but 8 waves
// (2 waves/SIMD) instead of 4 (1/SIMD): per-wave work halves, intra-SIMD overlap hides
// ds_read->MFMA chains and post-barrier staging gaps (m114). No atomics, no extra blocks.
// Staging: 24 x 1KB segments/chunk = 3 gld16/wave -> steady-state vmcnt(6) (2 chunks in
// flight), tail 3 -> 0. Swizzle identical (row&7 == l15&7 for all A/B reads).
__device__ inline void k_dist_stage(ushort* sm, int buf, int k0,
                                    const ushort* Zb, const ushort* mbh, const ushort* mbl,
                                    int w, int rr, int c8){
  int base = buf*12288;
#pragma unroll
  for(int j=0;j<3;j++){
    int s = 8*j + w;                 // 0..23, wave-uniform (w in 0..7)
    int row = (s&7)*8 + rr;          // row within 64-row tile
    int off = k0 + ((c8 ^ (row&7))<<3);   // pre-swizzled source chunk
    const ushort* src; int dst;
    if(s < 8){        src = Zb  + (size_t)row*DIM + off; dst = base + s*512; }
    else if(s < 16){  src = mbh + (size_t)row*DIM + off; dst = base + 4096 + (s-8)*512; }
    else {            src = mbl + (size_t)row*DIM + off; dst = base + 8192 + (s-16)*512; }
    gld16(src, sm + dst);
  }
}

__global__ __launch_bounds__(512,1) void k_dist(const ushort* __restrict__ mbh, const ushort* __restrict__ mbl,
                                                const ushort* __restrict__ Zhi, const float* __restrict__ munorm,
                                                ushort* __restrict__ Kbf){
  __shared__ __align__(16) ushort sm[49152];   // 96 KB: 4 x (A 8KB + Bh 8KB + Bl 8KB)
  int t = threadIdx.x;
  int w = t>>6, lane = t&63;
  int l15 = lane&15, q = lane>>4;
  int rr = lane>>3, c8 = lane&7;
  int e7 = l15&7;
  int wm = w>>2, wn = w&3;           // wave grid: 2 sample-halves x 4 way-quarters
  int b = blockIdx.x;
  const ushort* Zb = Zhi + (size_t)(NL + b*64)*DIM;
  float mn = munorm[16*wn + l15];
  f32x4 acc[2];
  acc[0] = (f32x4){0.f,0.f,0.f,0.f};
  acc[1] = (f32x4){0.f,0.f,0.f,0.f};

  // prologue: stage chunks 0,1,2 -> buf 0,1,2 (9 loads/wave outstanding)
  k_dist_stage(sm, 0, 0,   Zb, mbh, mbl, w, rr, c8);
  k_dist_stage(sm, 1, 64,  Zb, mbh, mbl, w, rr, c8);
  k_dist_stage(sm, 2, 128, Zb, mbh, mbl, w, rr, c8);

  int brow = 16*wn + l15;            // B-tile row = this lane's way
  for(int c=0;c<24;c++){
    // wait for chunk c to land, leave c+1/c+2 in flight (T4: never 0 in steady state)
    if(c < 22)      asm volatile("s_waitcnt vmcnt(6)" ::: "memory");
    else if(c==22)  asm volatile("s_waitcnt vmcnt(3)" ::: "memory");
    else            asm volatile("s_waitcnt vmcnt(0)" ::: "memory");
    __builtin_amdgcn_sched_barrier(0);
    __builtin_amdgcn_s_barrier();     // all waves: chunk c landed; compute(c-1) done
    __builtin_amdgcn_sched_barrier(0);
    if(c+3 < 24)
      k_dist_stage(sm, (c+3)&3, (c+3)*64, Zb, mbh, mbl, w, rr, c8);
    const ushort* tb = sm + (c&3)*12288;
#pragma unroll
    for(int kt=0;kt<2;kt++){
      int sw = ((kt*4 + q) ^ e7)<<3;   // read-side swizzle (matches staged source)
      short8 bh = *(const short8*)&tb[4096 + brow*64 + sw];
      short8 bl = *(const short8*)&tb[8192 + brow*64 + sw];
#pragma unroll
      for(int mt=0;mt<2;mt++){
        short8 a = *(const short8*)&tb[(wm*32 + mt*16 + l15)*64 + sw];
        acc[mt] = __builtin_amdgcn_mfma_f32_16x16x32_bf16(a, bh, acc[mt], 0,0,0);
        acc[mt] = __builtin_amdgcn_mfma_f32_16x16x32_bf16(a, bl, acc[mt], 0,0,0);
      }
    }
  }

  // tail: d2 = 1 + |mu|^2 - 2 s ; Kbf = bf16(exp(-10 sqrt(max(d2,0))))
  // C/D layout: col = lane&15 (way), row = (lane>>4)*4 + reg (sample within 16-tile)
#pragma unroll
  for(int mt=0;mt<2;mt++)
#pragma unroll
    for(int r=0;r<4;r++){
      float d2 = 1.0f + mn - 2.0f*acc[mt][r];
      Kbf[(size_t)(b*64 + wm*32 + mt*16 + q*4 + r)*NW + 16*wn + l15] =
        f2bf(expf(-10.0f * sqrtf(fmaxf(d2, 0.0f))));
    }
}

// ---------------- K7: persistent Sinkhorn (round-6 proven version, frozen) ----------------
// tmat[256][33] two-half transpose colsums + plain-load pipelined read-back. Butterfly
// (r5: 3x worse) and single-pass tmat[256][65] (r8: +10%) both regressed — do not touch.
__global__ __launch_bounds__(256,1) void k_sinkhorn(const ushort* __restrict__ Kbf,
                                                    ushort* __restrict__ MThi,
                                                    float* __restrict__ partials, int* __restrict__ stamps,
                                                    float* __restrict__ vprev, float* __restrict__ masksum){
  __shared__ __align__(16) float vsh[64];
  __shared__ float tmat[256][33];
  __shared__ float tq[8][64];
  __shared__ float tcol[64];
  __shared__ float mred[4];
  __shared__ float ctrl[1];
  int t = threadIdx.x, b = blockIdx.x;
  int iu = b*256 + t;
  bool active = iu < NU;
  float kr[64];
  if(active){
    const ushort* kp = Kbf + (size_t)iu*NW;
#pragma unroll
    for(int q=0;q<8;q++){
      short8 hh = *(const short8*)(kp + 8*q);
#pragma unroll
      for(int i=0;i<8;i++) kr[8*q+i] = bf2f((ushort)hh[i]);
    }
  } else {
#pragma unroll
    for(int j=0;j<64;j++) kr[j]=0.f;
  }
  if(t < 64) vsh[t] = vprev[t];
  float u = 1.0f, r_old = 0.0f;
  __syncthreads();
  int n = 0;
  while(true){
    // fp64 row dot: keeps the convergence residual off the fp32 noise floor (eps=1e-6)
    double s = 0.0;
#pragma unroll
    for(int q=0;q<16;q++){
      float4 vv = *(const float4*)&vsh[4*q];
      s += (double)kr[4*q]*vv.x + (double)kr[4*q+1]*vv.y + (double)kr[4*q+2]*vv.z + (double)kr[4*q+3]*vv.w;
    }
    float sf = (float)s;
    float r = u * sf;
    float diff = fabsf(r - r_old);
    float u_new = (active && sf > 0.f) ? 1.0f/sf : 0.0f;
    {
      float wmx = diff;
#pragma unroll
      for(int o=32;o;o>>=1) wmx = fmaxf(wmx, __shfl_xor(wmx,o));
      if((t&63)==0) mred[t>>6] = wmx;
    }
#pragma unroll
    for(int h=0;h<2;h++){
#pragma unroll
      for(int jj=0;jj<32;jj++) tmat[t][jj] = kr[32*h+jj]*u_new;
      __syncthreads();
      {
        int j = t & 31, q = t >> 5;
        float ps = 0.f;
#pragma unroll
        for(int rr=0;rr<32;rr++) ps += tmat[q*32+rr][j];
        tq[q][j] = ps;
      }
      __syncthreads();
      if(t < 32) tcol[32*h + t] = tq[0][t]+tq[1][t]+tq[2][t]+tq[3][t]+tq[4][t]+tq[5][t]+tq[6][t]+tq[7][t];
      __syncthreads();
    }
    int buf = n & 1;
    float* P = partials + buf*(SB_NB*66) + b*66;
    if(t < 64){
      __hip_atomic_store(&P[t], tcol[t], __ATOMIC_RELAXED, __HIP_MEMORY_SCOPE_AGENT);
    } else if(t == 64){
      float bm = fmaxf(fmaxf(mred[0],mred[1]), fmaxf(mred[2],mred[3]));
      __hip_atomic_store(&P[64], bm, __ATOMIC_RELAXED, __HIP_MEMORY_SCOPE_AGENT);
    }
    __syncthreads();
    if(t == 0){
      __threadfence();
      __hip_atomic_store(&stamps[b], n+1, __ATOMIC_RELEASE, __HIP_MEMORY_SCOPE_AGENT);
    }
    if(t < SB_NB){
      while(__hip_atomic_load(&stamps[t], __ATOMIC_ACQUIRE, __HIP_MEMORY_SCOPE_AGENT) <= n){}
    }
    __syncthreads();
    {
      int j = t & 63, q4 = t >> 6;
      float ps = 0.f, pm = 0.f;
      const float* PB = partials + buf*(SB_NB*66);
      // 12 unconditional plain loads (pipeline into one latency exposure) + uniform tail
#pragma unroll
      for(int i=0;i<12;i++){
        int bb = q4 + 4*i;            // max 3+44 = 47 < 49, always valid
        ps += PB[bb*66 + j];
        pm = fmaxf(pm, PB[bb*66 + 64]);
      }
      if(q4 == 0){                    // bb = 48 handled only by group 0 (wave-uniform)
        ps += PB[48*66 + j];
        pm = fmaxf(pm, PB[48*66 + 64]);
      }
      tq[q4][j] = ps;
      if(j==0) mred[q4] = pm;
    }
    __syncthreads();
    if(t==0) ctrl[0] = fmaxf(fmaxf(mred[0],mred[1]), fmaxf(mred[2],mred[3]));
    __syncthreads();
    float M = ctrl[0];
    if(M <= EPSC || n >= MAXIT) break;
    u = u_new; r_old = r; n++;
    if(t < 64) vsh[t] = (float)NQ / (tq[0][t]+tq[1][t]+tq[2][t]+tq[3][t]);
    __syncthreads();
  }
  // final plan colsums -> masksum
#pragma unroll
  for(int h=0;h<2;h++){
#pragma unroll
    for(int jj=0;jj<32;jj++) tmat[t][jj] = kr[32*h+jj]*u;
    __syncthreads();
    {
      int j = t & 31, q = t >> 5;
      float ps = 0.f;
#pragma unroll
      for(int rr=0;rr<32;rr++) ps += tmat[q*32+rr][j];
      tq[q][j] = ps;
    }
    __syncthreads();
    if(t < 32) tcol[32*h + t] = tq[0][t]+tq[1][t]+tq[2][t]+tq[3][t]+tq[4][t]+tq[5][t]+tq[6][t]+tq[7][t];
    __syncthreads();
  }
  if(t < 64) atomicAdd(&masksum[t], tcol[t]*vsh[t]);
  // store plan transposed, bf16 hi only (pitch NUP; 49*256 == NUP exactly)
  if(active){
#pragma unroll
    for(int j=0;j<64;j++)
      MThi[(size_t)j*NUP + iu] = f2bf(kr[j]*u*vsh[j]);
  } else {
#pragma unroll
    for(int j=0;j<64;j++)
      MThi[(size_t)j*NUP + iu] = 0;
  }
  if(b==0 && t<64) vprev[t] = vsh[t];
}

// ---------------- K8 v2: emus via MFMA, LDS-staged 4-deep global_load_lds ring ----------------
__device__ inline void k_emus_stage(ushort* sm, int buf, int k0,
                                    const ushort* Ab, const ushort* Bb,
                                    int w, int rr, int c8){
  int base = buf*8192;
#pragma unroll
  for(int j=0;j<4;j++){
    int s = 4*j + w;                 // 0..15, wave-uniform
    int row = (s&7)*8 + rr;          // row within 64-row tile
    int off = k0 + ((c8 ^ (row&7))<<3);   // pre-swizzled source chunk
    const ushort* src; int dst;
    if(s < 8){ src = Ab + (size_t)row*NUP + off; dst = base + s*512; }
    else     { src = Bb + (size_t)row*NUP + off; dst = base + 4096 + (s-8)*512; }
    gld16(src, sm + dst);
  }
}

__global__ __launch_bounds__(256,1) void k_emus(const ushort* __restrict__ MThi, const ushort* __restrict__ ZThi,
                                                float* __restrict__ part){
  __shared__ __align__(16) ushort sm[32768];   // 64 KB: 4 x (A 8KB + B 8KB)
  int t = threadIdx.x;
  int w = t>>6, lane = t&63;
  int l15 = lane&15, q = lane>>4;
  int rr = lane>>3, c8 = lane&7;
  int e7 = l15&7;
  int cx = blockIdx.x, iy = blockIdx.y;
  const ushort* Ab = MThi + iy*1792;                        // ways x cols
  const ushort* Bb = ZThi + (size_t)(cx*64)*NUP + iy*1792;  // dims x cols
  f32x4 acc[4];
#pragma unroll
  for(int mt=0;mt<4;mt++) acc[mt] = (f32x4){0.f,0.f,0.f,0.f};

  // prologue: stage chunks 0,1,2 -> buf 0,1,2 (12 loads/wave outstanding)
  k_emus_stage(sm, 0, 0,   Ab, Bb, w, rr, c8);
  k_emus_stage(sm, 1, 64,  Ab, Bb, w, rr, c8);
  k_emus_stage(sm, 2, 128, Ab, Bb, w, rr, c8);

  int brow = 16*w + l15;             // B-tile row = this lane's dim
  for(int c=0;c<28;c++){
    if(c < 26)      asm volatile("s_waitcnt vmcnt(8)" ::: "memory");
    else if(c==26)  asm volatile("s_waitcnt vmcnt(4)" ::: "memory");
    else            asm volatile("s_waitcnt vmcnt(0)" ::: "memory");
    __builtin_amdgcn_sched_barrier(0);
    __builtin_amdgcn_s_barrier();
    __builtin_amdgcn_sched_barrier(0);
    if(c+3 < 28)
      k_emus_stage(sm, (c+3)&3, (c+3)*64, Ab, Bb, w, rr, c8);
    const ushort* tb = sm + (c&3)*8192;
#pragma unroll
    for(int kt=0;kt<2;kt++){
      int sw = ((kt*4 + q) ^ e7)<<3;
      short8 bf = *(const short8*)&tb[4096 + brow*64 + sw];
#pragma unroll
      for(int mt=0;mt<4;mt++){
        short8 a = *(const short8*)&tb[(mt*16 + l15)*64 + sw];
        acc[mt] = __builtin_amdgcn_mfma_f32_16x16x32_bf16(a, bf, acc[mt], 0,0,0);
      }
    }
  }

  // store: way = mt*16 + q*4 + r (C/D row), dim = cx*64 + 16w + l15 (C/D col)
  float* dst = part + (size_t)iy*(NW*DIM);
#pragma unroll
  for(int mt=0;mt<4;mt++)
#pragma unroll
    for(int r=0;r<4;r++)
      dst[(size_t)(16*mt*1 + q*4 + r + 0)*DIM*0 + (size_t)(mt*16 + q*4 + r)*DIM + cx*64 + 16*w + l15] = acc[mt][r];
}

// ---------------- K9: fused mus update + next-epoch prep ----------------
__global__ void k_mus_step(float* __restrict__ mus, const float* __restrict__ emus_lab,
                           const float* __restrict__ part, float* munorm, float* masksum,
                           int* stamps, ushort* __restrict__ mbh, ushort* __restrict__ mbl){
  int w = blockIdx.x;
  float msum = masksum[w];
  float ss = 0.f;
#pragma unroll
  for(int q=0;q<6;q++){
    int c = threadIdx.x + 256*q;
    size_t idx = (size_t)w*DIM + c;
    float e = emus_lab[idx];
#pragma unroll
    for(int s=0;s<NSLAB;s++) e += part[(size_t)s*(NW*DIM) + idx];
    float nm = mus[idx] + ALPHA*(e/msum - mus[idx]);
    mus[idx] = nm;
    ss += nm*nm;
    ushort h = f2bf(nm);
    mbh[idx] = h;
    mbl[idx] = f2bf(nm - bf2f(h));
  }
  __shared__ float red[4];
  float wsu = wave_sum(ss);
  if((threadIdx.x&63)==0) red[threadIdx.x>>6]=wsu;
  __syncthreads();
  if(threadIdx.x==0){
    munorm[w] = red[0]+red[1]+red[2]+red[3];
    masksum[w] = 315.0f + 5.0f*expf(1.0f);
    if(w < SB_NB) stamps[w] = 0;
  }
}

// ---------------- K10a: labeled onehot rows ----------------
__global__ void k_out_lab(const int* __restrict__ labels, float* __restrict__ out){
  int idx = blockIdx.x*256 + threadIdx.x;
  if(idx < NL*NW){
    int i = idx >> 6, w = idx & 63;
    out[idx] = (labels[i]==w) ? 1.0f : 0.0f;
  }
}

// ---------------- K10b: unlabeled rows: out = log(plan) ----------------
__global__ __launch_bounds__(256) void k_out_u(const ushort* __restrict__ MThi, float* __restrict__ out){
  __shared__ float P[64][68];
  int b = blockIdx.x;
  int iu0 = b*64;
  int t = threadIdx.x;
  int w = t>>2, ch = (t&3)*16;
  const ushort* ph = MThi + (size_t)w*NUP + iu0 + ch;
  short8 h0 = *(const short8*)ph, h1 = *(const short8*)(ph+8);
#pragma unroll
  for(int k=0;k<8;k++){
    P[ch+k][w]   = logf(bf2f((ushort)h0[k]));
    P[ch+8+k][w] = logf(bf2f((ushort)h1[k]));
  }
  __syncthreads();
  int r = t>>2, c0 = (t&3)*16;
  float4* dst = (float4*)(out + (size_t)(NL + iu0 + r)*NW + c0);
#pragma unroll
  for(int g=0;g<4;g++) dst[g] = *(float4*)&P[r][c0+4*g];
}

// ---------------- K11: accuracy ----------------
__global__ void k_acc(const ushort* __restrict__ MThi, const int* __restrict__ labels, float* matchcount){
  int iu = blockIdx.x*256 + threadIdx.x;
  float m = 0.f;
  if(iu < NU){
    float best = -1.f; int bj = 0;
#pragma unroll 8
    for(int w=0;w<64;w++){
      float v = bf2f(MThi[(size_t)w*NUP + iu]);
      if(v > best){ best = v; bj = w; }
    }
    m = (labels[NL+iu] == bj) ? 1.f : 0.f;
  }
  float ws = wave_sum(m);
  __shared__ float red[4];
  if((threadIdx.x&63)==0) red[threadIdx.x>>6]=ws;
  __syncthreads();
  if(threadIdx.x==0) atomicAdd(matchcount, red[0]+red[1]+red[2]+red[3]);
}

// ---------------- K12 ----------------
__global__ void k_fin(const float* matchcount, float* __restrict__ out){
  out[(size_t)NTOT*NW]     = (*matchcount) * (1.0f/(float)NU);
  out[(size_t)NTOT*NW + 1] = 0.0f;
}

// ---------------- launch ----------------
extern "C" void kernel_launch(void* const* d_in, const int* in_sizes, int n_in,
                              void* d_out, int out_size, void* d_ws, size_t ws_size,
                              hipStream_t stream){
  const float* X = (const float*)d_in[0];
  const int* labels = (const int*)d_in[1];
  float* out = (float*)d_out;
  float* ws = (float*)d_ws;

  // ws layout (float offsets), total 20,757,576 fl = 83.0 MB (< proven-safe 85.94 MB)
  float*  matchcount = ws + 0;
  float*  munorm     = ws + 4;
  float*  masksum    = ws + 68;
  float*  vprev      = ws + 132;
  float*  csum_l     = ws + 196;
  float*  csum_u     = ws + 1732;
  int*    stamps     = (int*)(ws + 3268);        // 49 ints (region to 3332)
  float*  partials   = ws + 3332;                // 2*49*66 = 6468 -> 9800
  float*  Slc        = ws + 9800;                // 1536 -> 11336
  float*  mus        = ws + 11336;               // 98304 -> 109640
  float*  emus_lab   = ws + 109640;              // 98304 -> 207944
  ushort* mbh        = (ushort*)(ws + 207944);   // 49152 fl -> 257096
  ushort* mbl        = (ushort*)(ws + 257096);   // -> 306248
  // union region U (786,432 fl -> 1,092,680): lifetimes disjoint within an epoch:
  //   Kbf  (798,720 us = 399,360 fl)  live [k_dist -> k_sinkhorn load]
  //   part (7*98,304 = 688,128 fl)    live [k_emus -> k_mus_step]
  float*  U          = ws + 306248;
  ushort* Kbf        = (ushort*)U;
  float*  part       = U;
  ushort* MThi       = (ushort*)(ws + 1092680);  // 401,408 us = 200,704 fl -> 1,293,384
  ushort* Zhi        = (ushort*)(ws + 1293384);  // 9,830,400 fl -> 11,123,784
  ushort* ZThi       = (ushort*)(ws + 11123784); // 9,633,792 fl -> 20,757,576
  if(ws_size < (size_t)20757576*4) return;

  hipMemsetAsync(ws, 0, 3332*sizeof(float), stream);

  k_prep<<<3200,256,0,stream>>>(X, Zhi);
  k_colsum<<<dim3(3,100),256,0,stream>>>(Zhi, csum_l, csum_u);
  k_finalize_means<<<12,256,0,stream>>>(csum_l, csum_u);
  k_center<<<3200,256,0,stream>>>(Zhi, csum_l, csum_u);
  k_ztrans<<<dim3(195,24),256,0,stream>>>(Zhi, ZThi);
  k_ztpad<<<384,256,0,stream>>>(ZThi);
  k_mus_init<<<64,256,0,stream>>>(Zhi, mus);
  k_vinit<<<1,64,0,stream>>>(vprev);
  k_slc<<<6,256,0,stream>>>(mus, Slc);
  k_elab<<<384,256,0,stream>>>(mus, Slc, emus_lab);
  k_epoch_prep<<<64,256,0,stream>>>(mus, munorm, masksum, stamps, mbh, mbl);

  for(int e=0; e<=EPOCHS; e++){
    k_dist<<<195,512,0,stream>>>(mbh, mbl, Zhi, munorm, Kbf);
    k_sinkhorn<<<SB_NB,256,0,stream>>>(Kbf, MThi, partials, stamps, vprev, masksum);
    if(e < EPOCHS){
      k_emus<<<dim3(24,NSLAB),256,0,stream>>>(MThi, ZThi, part);
      k_mus_step<<<64,256,0,stream>>>(mus, emus_lab, part, munorm, masksum, stamps, mbh, mbl);
    }
  }
  k_out_lab<<<80,256,0,stream>>>(labels, out);
  k_out_u<<<195,256,0,stream>>>(MThi, out);
  k_acc<<<49,256,0,stream>>>(MThi, labels, matchcount);
  k_fin<<<1,1,0,stream>>>(matchcount, out);
}